// Round 9
// baseline (1074.437 us; speedup 1.0000x reference)
//
#include <hip/hip_runtime.h>
#include <hip/hip_bf16.h>

typedef __hip_bfloat16 bf16;
typedef __attribute__((ext_vector_type(8))) short v8s;
typedef __attribute__((ext_vector_type(4))) float v4f;

#define N_NODES 100000
#define N_EDGES 1600000
#define LN_EPS 1e-5f

// f32 param arena offsets (elements)
#define OFF_CONV_W      0
#define OFF_CONV_B      81
#define OFF_CONV_SW     84
#define OFF_CONV_SB     165
#define OFF_LIN_W       168
#define OFF_LIN_B       31272
#define OFF_LIN_SW      31400
#define OFF_LIN_SB      62504
#define OFF_SAGE_LW     62632
#define OFF_SAGE_LB     111784
#define OFF_SAGE_RW     112168
#define OFF_LN_G        161320
#define OFF_LN_B        161704
#define OFF_MLP_W1      162088
#define OFF_MLP_B1      178472
#define OFF_MLP_W2      178600
#define OFF_MLP_B2      179240
#define PARAM_TOTAL     179245

#define WTL_N 65536     // [256 f][256 k]  conv-linear (f<128: lin_w, f>=128: lin_self_w)
#define WTS_N 98304     // 3 x [128 f][256 k]  sage (k<128: lw, k>=128: rw)
#define WTM_N 16384     // [128 f][128 k]  mlp_w1

#define CVT2_BLOCKS 704    // (WTL_N+WTS_N+WTM_N)/256
#define DEG_BLOCKS  6250   // 1600000/256

__device__ __forceinline__ unsigned short f2b(float f) {
    bf16 h = __float2bfloat16(f);
    return __builtin_bit_cast(unsigned short, h);
}
__device__ __forceinline__ float blo(unsigned u) { return __uint_as_float(u << 16); }
__device__ __forceinline__ float bhi(unsigned u) { return __uint_as_float(u & 0xffff0000u); }
__device__ __forceinline__ unsigned pack2(float lo, float hi) {
    return (unsigned)f2b(lo) | ((unsigned)f2b(hi) << 16);
}

struct Ptr17 { const void* p[17]; };

// ---------------- dtype detection ----------------
__global__ void detect_kernel(const unsigned short* __restrict__ xw,
                              const unsigned int* __restrict__ ew,
                              int* __restrict__ flags) {
    __shared__ int sawBigExp, sawHigh;
    if (threadIdx.x == 0) { sawBigExp = 0; sawHigh = 0; }
    __syncthreads();
    int localBig = 0, localHigh = 0;
    for (int i = threadIdx.x; i < 65536; i += 256) {
        unsigned e = (xw[i] >> 7) & 0xFF;
        if (e >= 0xF0) localBig = 1;
    }
    for (int i = threadIdx.x; i < 8192; i += 256) {
        if (ew[2 * i + 1] != 0) localHigh = 1;
    }
    if (localBig) atomicOr(&sawBigExp, 1);
    if (localHigh) atomicOr(&sawHigh, 1);
    __syncthreads();
    if (threadIdx.x == 0) { flags[0] = sawBigExp; flags[1] = sawHigh ? 0 : 1; }
}

// ---------------- convert all float params to f32 arena ----------------
__global__ void cvt_params_kernel(Ptr17 ptrs, const int* __restrict__ flags,
                                  float* __restrict__ dst) {
    int i = blockIdx.x * 256 + threadIdx.x;
    if (i >= PARAM_TOTAL) return;
    const int ksz[17] = {81,3,81,3,31104,128,31104,128,49152,384,49152,384,384,16384,128,640,5};
    int seg = 0, off = i;
    while (off >= ksz[seg]) { off -= ksz[seg]; ++seg; }
    float v;
    if (flags[0]) v = ((const float*)ptrs.p[seg])[off];
    else          v = __bfloat162float(((const bf16*)ptrs.p[seg])[off]);
    dst[i] = v;
}

// ---------------- edge loads ----------------
__device__ __forceinline__ int ld_edge(const int* __restrict__ ew, size_t elem, int isi64) {
    size_t idx = isi64 ? (elem * 2) : elem;
    return ew[idx];
}

// ---------------- build bf16 transposed weight arenas, FUSED with degree count -------
// Zero-LDS kernel -> the appended degree blocks run at full occupancy (R8 lesson:
// grafting degree onto the 29KB-LDS conv kernel capped it at 5 blocks/CU, +44us).
__global__ void cvt2_deg_kernel(const float* __restrict__ P,
                                unsigned short* __restrict__ wtl,
                                unsigned short* __restrict__ wts,
                                unsigned short* __restrict__ wtm,
                                const int* __restrict__ ew, const int* __restrict__ flags,
                                int* __restrict__ deg) {
    if (blockIdx.x >= CVT2_BLOCKS) {
        int e = (blockIdx.x - CVT2_BLOCKS) * 256 + threadIdx.x;
        if (e < N_EDGES) {
            int d = ld_edge(ew, (size_t)N_EDGES + e, flags[1]);
            if ((unsigned)d < N_NODES) atomicAdd(&deg[d], 1);
        }
        return;
    }
    int i = blockIdx.x * 256 + threadIdx.x;
    if (i < WTL_N) {
        int f = i >> 8, k = i & 255;
        float v = 0.f;
        if (k < 243) v = (f < 128) ? P[OFF_LIN_W + k * 128 + f]
                                   : P[OFF_LIN_SW + k * 128 + (f - 128)];
        wtl[i] = f2b(v);
    } else if (i < WTL_N + WTS_N) {
        int j = i - WTL_N; int l = j >> 15; int r = j & 32767; int f = r >> 8; int k = r & 255;
        float v = (k < 128) ? P[OFF_SAGE_LW + l * 16384 + k * 128 + f]
                            : P[OFF_SAGE_RW + l * 16384 + (k - 128) * 128 + f];
        wts[j] = f2b(v);
    } else if (i < WTL_N + WTS_N + WTM_N) {
        int j = i - WTL_N - WTS_N; int f = j >> 7, k = j & 127;
        wtm[j] = f2b(P[OFF_MLP_W1 + k * 128 + f]);
    }
}

// ---------------- Stage 1: conv+relu (VALU) -> 243->256 linear (MFMA), fused ----------------
// R4-verified variant (183-185us): 16-node tile, 320 threads, xs flat bf16, scalar conv
// reads. Vectorized-LDS variant regressed (R6); degree-fusion regressed (R8).
__global__ __launch_bounds__(320) void conv_lin_kernel(
    const void* __restrict__ x, const float* __restrict__ P,
    const unsigned short* __restrict__ wtl, const int* __restrict__ flags,
    unsigned short* __restrict__ xnb, float* __restrict__ selfh)
{
    __shared__ unsigned short xs[5808];           // 16 nodes x 363 bf16, flat
    __shared__ unsigned short ysb[16][2][256];    // relu(conv) bf16, K padded to 256
    __shared__ float wc[2][81];
    __shared__ float bc[2][3];
    int tid = threadIdx.x;
    int n0 = blockIdx.x * 16;

    if (tid < 81) { wc[0][tid] = P[OFF_CONV_W + tid]; wc[1][tid] = P[OFF_CONV_SW + tid]; }
    else if (tid < 84) { int o = tid - 81; bc[0][o] = P[OFF_CONV_B + o]; bc[1][o] = P[OFF_CONV_SB + o]; }

    // zero ysb K padding 243..255 (16 j x 2 p x 13 k)
    for (int i = tid; i < 416; i += 320) {
        int j = i / 26, r2 = i % 26, p = r2 / 13, k = 243 + (r2 % 13);
        ysb[j][p][k] = 0;
    }

    if (flags[0]) {
        const float* xf = (const float*)x + (size_t)n0 * 363;
        for (int i = tid; i < 5808; i += 320) xs[i] = f2b(xf[i]);
    } else {
        const uint4* xsrc = (const uint4*)((const unsigned short*)x + (size_t)n0 * 363);
        uint4* xd = (uint4*)xs;
        for (int i = tid; i < 726; i += 320) xd[i] = xsrc[i];
    }
    __syncthreads();

    // conv: one unit per thread: (node j, path p, output row oi) -> 27 outputs
    if (tid < 288) {
        int j = tid / 18, rem = tid % 18;
        int p = rem / 9, oi = rem % 9;
        float acc[27];
        #pragma unroll
        for (int o = 0; o < 3; o++) {
            float b = bc[p][o];
            #pragma unroll
            for (int oj = 0; oj < 9; oj++) acc[o * 9 + oj] = b;
        }
        #pragma unroll
        for (int c = 0; c < 3; c++) {
            #pragma unroll
            for (int ki = 0; ki < 3; ki++) {
                float xr[11];
                const unsigned short* row = &xs[j * 363 + c * 121 + (oi + ki) * 11];
                #pragma unroll
                for (int t = 0; t < 11; t++) xr[t] = blo(row[t]);
                #pragma unroll
                for (int o = 0; o < 3; o++) {
                    int wb = o * 27 + c * 9 + ki * 3;
                    float w0 = wc[p][wb], w1 = wc[p][wb + 1], w2 = wc[p][wb + 2];
                    #pragma unroll
                    for (int oj = 0; oj < 9; oj++)
                        acc[o * 9 + oj] += xr[oj] * w0 + xr[oj + 1] * w1 + xr[oj + 2] * w2;
                }
            }
        }
        #pragma unroll
        for (int o = 0; o < 3; o++)
            #pragma unroll
            for (int oj = 0; oj < 9; oj++)
                ysb[j][p][o * 81 + oi * 9 + oj] = f2b(fmaxf(acc[o * 9 + oj], 0.f));
    }
    __syncthreads();

    // MFMA: [16 nodes][256 k] x [256 k][256 f]; waves 0-1 -> path0 (f 0..127), 2-3 -> path1
    int wave = tid >> 6, lane = tid & 63, quad = lane >> 4, col = lane & 15;
    if (wave < 4) {
        int p = wave >> 1;
        v4f acc[4];
        #pragma unroll
        for (int t = 0; t < 4; t++) { acc[t][0] = 0.f; acc[t][1] = 0.f; acc[t][2] = 0.f; acc[t][3] = 0.f; }
        for (int s = 0; s < 8; s++) {
            int kq = s * 32 + quad * 8;
            v8s a = *(const v8s*)&ysb[col][p][kq];
            #pragma unroll
            for (int t = 0; t < 4; t++) {
                int f = (wave * 4 + t) * 16 + col;
                v8s b = *(const v8s*)&wtl[(size_t)f * 256 + kq];
                acc[t] = __builtin_amdgcn_mfma_f32_16x16x32_bf16(a, b, acc[t], 0, 0, 0);
            }
        }
        #pragma unroll
        for (int t = 0; t < 4; t++) {
            int f = (wave * 4 + t) * 16 + col;
            #pragma unroll
            for (int r = 0; r < 4; r++) {
                int node = n0 + quad * 4 + r;
                float v = acc[t][r];
                if (p == 0) xnb[(size_t)node * 128 + f] = f2b(v + P[OFF_LIN_B + f]);
                else        selfh[(size_t)node * 128 + (f - 128)] = v + P[OFF_LIN_SB + (f - 128)];
            }
        }
    }
}

// ---------------- CSR build ----------------
__global__ __launch_bounds__(1024) void scanA(const int* __restrict__ deg, int* __restrict__ rowptr,
                                              float* __restrict__ cntf, int* __restrict__ bsum) {
    __shared__ int s[1024];
    int tid = threadIdx.x;
    int i = blockIdx.x * 1024 + tid;
    int v = (i < N_NODES) ? deg[i] : 0;
    s[tid] = v;
    __syncthreads();
    for (int off = 1; off < 1024; off <<= 1) {
        int t = (tid >= off) ? s[tid - off] : 0;
        __syncthreads();
        s[tid] += t;
        __syncthreads();
    }
    if (i < N_NODES) {
        rowptr[i] = s[tid] - v;
        cntf[i] = (float)(v < 1 ? 1 : v);
    }
    if (tid == 1023) bsum[blockIdx.x] = s[1023];
}

__global__ void scanB(const int* __restrict__ bsum, int* __restrict__ boff, int nb, int* __restrict__ rowptr_end) {
    if (threadIdx.x == 0 && blockIdx.x == 0) {
        int run = 0;
        for (int i = 0; i < nb; i++) { boff[i] = run; run += bsum[i]; }
        *rowptr_end = run;
    }
}

__global__ __launch_bounds__(1024) void scanC(int* __restrict__ rowptr, const int* __restrict__ boff,
                                              int* __restrict__ cursor) {
    int i = blockIdx.x * 1024 + threadIdx.x;
    if (i < N_NODES) {
        int v = rowptr[i] + boff[blockIdx.x];
        rowptr[i] = v;
        cursor[i] = v;
    }
}

__global__ void fill_kernel(const int* __restrict__ ew, const int* __restrict__ flags,
                            int* __restrict__ cursor, int* __restrict__ csr) {
    int e = blockIdx.x * blockDim.x + threadIdx.x;
    if (e < N_EDGES) {
        int isi64 = flags[1];
        int s = ld_edge(ew, (size_t)e, isi64);
        int d = ld_edge(ew, (size_t)N_EDGES + e, isi64);
        if ((unsigned)d < N_NODES) {
            int p = atomicAdd(&cursor[d], 1);
            if ((unsigned)p < N_EDGES)
                csr[p] = ((unsigned)s < N_NODES) ? (s | ((s == d) ? (int)0x80000000 : 0)) : -1;
        }
    }
}

// ---------------- agg0 + relu + LN0 ----------------
__global__ __launch_bounds__(256) void agg0ln_kernel(const unsigned short* __restrict__ xnb,
        const float* __restrict__ selfh, const int* __restrict__ rowptr, const int* __restrict__ csr,
        const float* __restrict__ lng, const float* __restrict__ lnb,
        unsigned short* __restrict__ zb) {
    int wave = threadIdx.x >> 6, lane = threadIdx.x & 63;
    int g = lane >> 4, c = lane & 15;
    int n = blockIdx.x * 4 + wave;
    int beg = rowptr[n], end = rowptr[n + 1];
    float a[8];
    #pragma unroll
    for (int i = 0; i < 8; i++) a[i] = 0.f;
    const uint4* x4 = (const uint4*)xnb;
    for (int b = beg; b < end; b += 64) {
        int bl = b + lane;
        int my = (bl < end) ? csr[bl] : -1;
        int nb = end - b; if (nb > 64) nb = 64;
        for (int i = 0; i < nb; i += 16) {
            int sv0 = __shfl(my, i + g, 64);
            int sv1 = __shfl(my, i + 4 + g, 64);
            int sv2 = __shfl(my, i + 8 + g, 64);
            int sv3 = __shfl(my, i + 12 + g, 64);
            bool va0 = ((unsigned)sv0 < N_NODES);
            bool va1 = ((unsigned)sv1 < N_NODES);
            bool va2 = ((unsigned)sv2 < N_NODES);
            bool va3 = ((unsigned)sv3 < N_NODES);
            uint4 v0 = x4[(size_t)(va0 ? sv0 : 0) * 16 + c];
            uint4 v1 = x4[(size_t)(va1 ? sv1 : 0) * 16 + c];
            uint4 v2 = x4[(size_t)(va2 ? sv2 : 0) * 16 + c];
            uint4 v3 = x4[(size_t)(va3 ? sv3 : 0) * 16 + c];
            if (va0) {
                a[0] += blo(v0.x); a[1] += bhi(v0.x);
                a[2] += blo(v0.y); a[3] += bhi(v0.y);
                a[4] += blo(v0.z); a[5] += bhi(v0.z);
                a[6] += blo(v0.w); a[7] += bhi(v0.w);
            }
            if (va1) {
                a[0] += blo(v1.x); a[1] += bhi(v1.x);
                a[2] += blo(v1.y); a[3] += bhi(v1.y);
                a[4] += blo(v1.z); a[5] += bhi(v1.z);
                a[6] += blo(v1.w); a[7] += bhi(v1.w);
            }
            if (va2) {
                a[0] += blo(v2.x); a[1] += bhi(v2.x);
                a[2] += blo(v2.y); a[3] += bhi(v2.y);
                a[4] += blo(v2.z); a[5] += bhi(v2.z);
                a[6] += blo(v2.w); a[7] += bhi(v2.w);
            }
            if (va3) {
                a[0] += blo(v3.x); a[1] += bhi(v3.x);
                a[2] += blo(v3.y); a[3] += bhi(v3.y);
                a[4] += blo(v3.z); a[5] += bhi(v3.z);
                a[6] += blo(v3.w); a[7] += bhi(v3.w);
            }
        }
    }
    #pragma unroll
    for (int i = 0; i < 8; i++) {
        a[i] += __shfl_xor(a[i], 16, 64);
        a[i] += __shfl_xor(a[i], 32, 64);
    }
    if (g == 0) {
        const float4* s4 = (const float4*)(selfh + (size_t)n * 128 + c * 8);
        float4 s0 = s4[0], s1 = s4[1];
        float v[8];
        v[0] = s0.x + a[0]; v[1] = s0.y + a[1]; v[2] = s0.z + a[2]; v[3] = s0.w + a[3];
        v[4] = s1.x + a[4]; v[5] = s1.y + a[5]; v[6] = s1.z + a[6]; v[7] = s1.w + a[7];
        float s = 0.f, sq = 0.f;
        #pragma unroll
        for (int i = 0; i < 8; i++) {
            v[i] = fmaxf(v[i], 0.f);
            s += v[i]; sq += v[i] * v[i];
        }
        #pragma unroll
        for (int m = 8; m >= 1; m >>= 1) {
            s  += __shfl_xor(s, m, 64);
            sq += __shfl_xor(sq, m, 64);
        }
        float mu = s * (1.f / 128.f);
        float var = sq * (1.f / 128.f) - mu * mu;
        float is = rsqrtf(var + LN_EPS);
        const float4* g4 = (const float4*)(lng + c * 8);
        const float4* b4 = (const float4*)(lnb + c * 8);
        float4 g0 = g4[0], g1 = g4[1], b0 = b4[0], b1 = b4[1];
        float z[8];
        z[0] = (v[0] - mu) * is * g0.x + b0.x; z[1] = (v[1] - mu) * is * g0.y + b0.y;
        z[2] = (v[2] - mu) * is * g0.z + b0.z; z[3] = (v[3] - mu) * is * g0.w + b0.w;
        z[4] = (v[4] - mu) * is * g1.x + b1.x; z[5] = (v[5] - mu) * is * g1.y + b1.y;
        z[6] = (v[6] - mu) * is * g1.z + b1.z; z[7] = (v[7] - mu) * is * g1.w + b1.w;
        uint4 o;
        o.x = pack2(z[0], z[1]); o.y = pack2(z[2], z[3]);
        o.z = pack2(z[4], z[5]); o.w = pack2(z[6], z[7]);
        ((uint4*)zb)[(size_t)n * 16 + c] = o;
    }
}

// ---------------- gather helper: mean-aggregate 4 nodes per wave into LDS ----------------
__device__ __forceinline__ void sage_gather(const unsigned short* __restrict__ cur,
        const int* __restrict__ rowptr, const int* __restrict__ csr,
        const float* __restrict__ cntf, int n0, int wave, int lane, int g, int c,
        unsigned short al[16][128]) {
    const uint4* z4 = (const uint4*)cur;
    for (int q = 0; q < 4; q++) {
        int jj = wave * 4 + q;
        int n = n0 + jj;
        int beg = rowptr[n], end = rowptr[n + 1];
        float a[8];
        #pragma unroll
        for (int i = 0; i < 8; i++) a[i] = 0.f;
        for (int b = beg; b < end; b += 64) {
            int bl = b + lane;
            int my = (bl < end) ? csr[bl] : -1;
            int nb = end - b; if (nb > 64) nb = 64;
            for (int i = 0; i < nb; i += 16) {
                int sv0 = __shfl(my, i + g, 64) & 0x7fffffff;      // SAGE keeps self loops
                int sv1 = __shfl(my, i + 4 + g, 64) & 0x7fffffff;
                int sv2 = __shfl(my, i + 8 + g, 64) & 0x7fffffff;
                int sv3 = __shfl(my, i + 12 + g, 64) & 0x7fffffff;
                bool va0 = (sv0 < N_NODES);
                bool va1 = (sv1 < N_NODES);
                bool va2 = (sv2 < N_NODES);
                bool va3 = (sv3 < N_NODES);
                uint4 v0 = z4[(size_t)(va0 ? sv0 : 0) * 16 + c];
                uint4 v1 = z4[(size_t)(va1 ? sv1 : 0) * 16 + c];
                uint4 v2 = z4[(size_t)(va2 ? sv2 : 0) * 16 + c];
                uint4 v3 = z4[(size_t)(va3 ? sv3 : 0) * 16 + c];
                if (va0) {
                    a[0] += blo(v0.x); a[1] += bhi(v0.x);
                    a[2] += blo(v0.y); a[3] += bhi(v0.y);
                    a[4] += blo(v0.z); a[5] += bhi(v0.z);
                    a[6] += blo(v0.w); a[7] += bhi(v0.w);
                }
                if (va1) {
                    a[0] += blo(v1.x); a[1] += bhi(v1.x);
                    a[2] += blo(v1.y); a[3] += bhi(v1.y);
                    a[4] += blo(v1.z); a[5] += bhi(v1.z);
                    a[6] += blo(v1.w); a[7] += bhi(v1.w);
                }
                if (va2) {
                    a[0] += blo(v2.x); a[1] += bhi(v2.x);
                    a[2] += blo(v2.y); a[3] += bhi(v2.y);
                    a[4] += blo(v2.z); a[5] += bhi(v2.z);
                    a[6] += blo(v2.w); a[7] += bhi(v2.w);
                }
                if (va3) {
                    a[0] += blo(v3.x); a[1] += bhi(v3.x);
                    a[2] += blo(v3.y); a[3] += bhi(v3.y);
                    a[4] += blo(v3.z); a[5] += bhi(v3.z);
                    a[6] += blo(v3.w); a[7] += bhi(v3.w);
                }
            }
        }
        #pragma unroll
        for (int i = 0; i < 8; i++) {
            a[i] += __shfl_xor(a[i], 16, 64);
            a[i] += __shfl_xor(a[i], 32, 64);
        }
        if (g == 0) {
            float inv = 1.f / cntf[n];
            uint4 o;
            o.x = pack2(a[0] * inv, a[1] * inv); o.y = pack2(a[2] * inv, a[3] * inv);
            o.z = pack2(a[4] * inv, a[5] * inv); o.w = pack2(a[6] * inv, a[7] * inv);
            ((uint4*)&al[jj][0])[c] = o;
        }
    }
}

// ---------------- FUSED SAGE layer 0/1: gather + MFMA + relu+LN ----------------
__global__ __launch_bounds__(256) void sagefused_kernel(
        const unsigned short* __restrict__ cur,
        const int* __restrict__ rowptr, const int* __restrict__ csr,
        const float* __restrict__ cntf, const unsigned short* __restrict__ wts,
        const float* __restrict__ lb, const float* __restrict__ lng, const float* __restrict__ lnb,
        unsigned short* __restrict__ nxt) {
    __shared__ unsigned short al[16][128];   // bf16 mean-aggregated features
    __shared__ float hb[16][128];
    int tid = threadIdx.x;
    int n0 = blockIdx.x * 16;
    int wave = tid >> 6, lane = tid & 63;
    int g = lane >> 4, c = lane & 15;

    sage_gather(cur, rowptr, csr, cntf, n0, wave, lane, g, c, al);
    __syncthreads();

    // MFMA (concat-K: agg from LDS, root from cur)
    int quad = g, col = c;
    int nodeA = n0 + col;
    v4f acc[2];
    #pragma unroll
    for (int t = 0; t < 2; t++) { acc[t][0] = 0.f; acc[t][1] = 0.f; acc[t][2] = 0.f; acc[t][3] = 0.f; }
    #pragma unroll
    for (int s = 0; s < 8; s++) {
        int kq = s * 32 + quad * 8;
        const unsigned short* abase = (s < 4) ? &al[col][kq]
                                              : (cur + (size_t)nodeA * 128 + (kq - 128));
        v8s a = *(const v8s*)abase;
        #pragma unroll
        for (int t = 0; t < 2; t++) {
            int f = (wave * 2 + t) * 16 + col;
            v8s b = *(const v8s*)&wts[(size_t)f * 256 + kq];
            acc[t] = __builtin_amdgcn_mfma_f32_16x16x32_bf16(a, b, acc[t], 0, 0, 0);
        }
    }
    #pragma unroll
    for (int t = 0; t < 2; t++) {
        int f = (wave * 2 + t) * 16 + col;
        float bias = lb[f];
        #pragma unroll
        for (int r = 0; r < 4; r++)
            hb[quad * 4 + r][f] = acc[t][r] + bias;
    }
    __syncthreads();

    // relu + LN
    #pragma unroll
    for (int jj = 0; jj < 4; jj++) {
        int j = wave * 4 + jj;
        int node = n0 + j;
        float v0 = hb[j][2 * lane], v1 = hb[j][2 * lane + 1];
        float r0 = fmaxf(v0, 0.f), r1 = fmaxf(v1, 0.f);
        float s = r0 + r1, sq = r0 * r0 + r1 * r1;
        #pragma unroll
        for (int m = 32; m >= 1; m >>= 1) {
            s  += __shfl_xor(s, m, 64);
            sq += __shfl_xor(sq, m, 64);
        }
        float mu = s * (1.f / 128.f);
        float var = sq * (1.f / 128.f) - mu * mu;
        float inv = rsqrtf(var + LN_EPS);
        float z0 = (r0 - mu) * inv * lng[2 * lane]     + lnb[2 * lane];
        float z1 = (r1 - mu) * inv * lng[2 * lane + 1] + lnb[2 * lane + 1];
        ((unsigned int*)nxt)[(size_t)node * 64 + lane] = pack2(z0, z1);
    }
}

// ---------------- FUSED last SAGE layer + MLP head + log_softmax + emb out ----------------
__global__ __launch_bounds__(256) void sagemlp_kernel(
        const unsigned short* __restrict__ cur,
        const int* __restrict__ rowptr, const int* __restrict__ csr,
        const float* __restrict__ cntf, const unsigned short* __restrict__ wts,
        const float* __restrict__ lb, const unsigned short* __restrict__ wtm,
        const float* __restrict__ P, const int* __restrict__ flags,
        void* __restrict__ out) {
    __shared__ unsigned short al[16][128];
    __shared__ float hb[16][128];
    __shared__ unsigned short rb[16][128];
    __shared__ float mb[16][128];
    __shared__ float lg[16][5];
    int tid = threadIdx.x;
    int n0 = blockIdx.x * 16;
    int wave = tid >> 6, lane = tid & 63;
    int g = lane >> 4, c = lane & 15;
    int isf = flags[0];

    sage_gather(cur, rowptr, csr, cntf, n0, wave, lane, g, c, al);
    __syncthreads();

    // SAGE MFMA -> hb (final h, f32)
    int quad = g, col = c;
    int nodeA = n0 + col;
    v4f acc[2];
    #pragma unroll
    for (int t = 0; t < 2; t++) { acc[t][0] = 0.f; acc[t][1] = 0.f; acc[t][2] = 0.f; acc[t][3] = 0.f; }
    #pragma unroll
    for (int s = 0; s < 8; s++) {
        int kq = s * 32 + quad * 8;
        const unsigned short* abase = (s < 4) ? &al[col][kq]
                                              : (cur + (size_t)nodeA * 128 + (kq - 128));
        v8s a = *(const v8s*)abase;
        #pragma unroll
        for (int t = 0; t < 2; t++) {
            int f = (wave * 2 + t) * 16 + col;
            v8s b = *(const v8s*)&wts[(size_t)f * 256 + kq];
            acc[t] = __builtin_amdgcn_mfma_f32_16x16x32_bf16(a, b, acc[t], 0, 0, 0);
        }
    }
    #pragma unroll
    for (int t = 0; t < 2; t++) {
        int f = (wave * 2 + t) * 16 + col;
        float bias = lb[f];
        #pragma unroll
        for (int r = 0; r < 4; r++)
            hb[quad * 4 + r][f] = acc[t][r] + bias;
    }
    __syncthreads();

    // mlp front: emb output write + relu -> rb (bf16)
    for (int i = tid; i < 16 * 64; i += 256) {
        int j = i >> 6, q = i & 63;
        float vx = hb[j][2 * q], vy = hb[j][2 * q + 1];
        size_t oi = (size_t)(n0 + j) * 128 + 2 * q;
        if (isf) { ((float*)out)[oi] = vx; ((float*)out)[oi + 1] = vy; }
        else ((unsigned int*)out)[oi >> 1] = pack2(vx, vy);
        rb[j][2 * q]     = f2b(fmaxf(vx, 0.f));
        rb[j][2 * q + 1] = f2b(fmaxf(vy, 0.f));
    }
    __syncthreads();

    // mlp MFMA (rb x wtm)
    v4f acc2[2];
    #pragma unroll
    for (int t = 0; t < 2; t++) { acc2[t][0] = 0.f; acc2[t][1] = 0.f; acc2[t][2] = 0.f; acc2[t][3] = 0.f; }
    #pragma unroll
    for (int s = 0; s < 4; s++) {
        int kq = s * 32 + quad * 8;
        v8s a = *(const v8s*)&rb[col][kq];
        #pragma unroll
        for (int t = 0; t < 2; t++) {
            int f = (wave * 2 + t) * 16 + col;
            v8s b = *(const v8s*)&wtm[(size_t)f * 128 + kq];
            acc2[t] = __builtin_amdgcn_mfma_f32_16x16x32_bf16(a, b, acc2[t], 0, 0, 0);
        }
    }
    #pragma unroll
    for (int t = 0; t < 2; t++) {
        int f = (wave * 2 + t) * 16 + col;
        float bias = P[OFF_MLP_B1 + f];
        #pragma unroll
        for (int r = 0; r < 4; r++)
            mb[quad * 4 + r][f] = acc2[t][r] + bias;
    }
    __syncthreads();

    if (tid < 80) {
        int j = tid / 5, o = tid - (tid / 5) * 5;
        float a = P[OFF_MLP_B2 + o];
        for (int k = 0; k < 128; k++) a += mb[j][k] * P[OFF_MLP_W2 + k * 5 + o];
        lg[j][o] = a;
    }
    __syncthreads();
    if (tid < 16) {
        int j = tid;
        float mx = lg[j][0];
        #pragma unroll
        for (int o = 1; o < 5; o++) mx = fmaxf(mx, lg[j][o]);
        float se = 0.f;
        #pragma unroll
        for (int o = 0; o < 5; o++) se += expf(lg[j][o] - mx);
        float lse = mx + logf(se);
        size_t base = (size_t)N_NODES * 128 + (size_t)(n0 + j) * 5;
        #pragma unroll
        for (int o = 0; o < 5; o++) {
            float v = lg[j][o] - lse;
            if (isf) ((float*)out)[base + o] = v;
            else     ((bf16*)out)[base + o] = __float2bfloat16(v);
        }
    }
}

extern "C" void kernel_launch(void* const* d_in, const int* in_sizes, int n_in,
                              void* d_out, int out_size, void* d_ws, size_t ws_size,
                              hipStream_t stream) {
    const void* x  = d_in[0];
    const int*  ew = (const int*)d_in[1];

    Ptr17 ptrs;
    for (int i = 0; i < 17; i++) ptrs.p[i] = d_in[2 + i];

    char* w = (char*)d_ws;
    auto carve = [&](size_t bytes) { char* r = w; w += (bytes + 255) & ~(size_t)255; return r; };
    float*          bufS  = (float*)carve((size_t)N_NODES * 128 * 4);   // selfh
    unsigned short* xnb   = (unsigned short*)carve((size_t)N_NODES * 128 * 2);
    unsigned short* zb    = (unsigned short*)carve((size_t)N_NODES * 128 * 2);
    unsigned short* aggb  = (unsigned short*)carve((size_t)N_NODES * 128 * 2);
    float*          pf32  = (float*)carve((size_t)PARAM_TOTAL * 4);
    unsigned short* wtl   = (unsigned short*)carve((size_t)WTL_N * 2);
    unsigned short* wts   = (unsigned short*)carve((size_t)WTS_N * 2);
    unsigned short* wtm   = (unsigned short*)carve((size_t)WTM_N * 2);
    int*   deg    = (int*)carve((size_t)N_NODES * 4);
    int*   rowptr = (int*)carve((size_t)(N_NODES + 64) * 4);
    int*   cursor = (int*)carve((size_t)N_NODES * 4);
    float* cntf   = (float*)carve((size_t)N_NODES * 4);
    int*   bsum   = (int*)carve(512);
    int*   boff   = (int*)carve(512);
    int*   flags  = (int*)carve(256);
    int*   csr    = (int*)carve((size_t)N_EDGES * 4);

    const int SCAN_BLOCKS = (N_NODES + 1023) / 1024;

    detect_kernel<<<1, 256, 0, stream>>>((const unsigned short*)x, (const unsigned int*)ew, flags);
    hipMemsetAsync(deg, 0, (size_t)N_NODES * 4, stream);
    cvt_params_kernel<<<(PARAM_TOTAL + 255) / 256, 256, 0, stream>>>(ptrs, flags, pf32);
    cvt2_deg_kernel<<<CVT2_BLOCKS + DEG_BLOCKS, 256, 0, stream>>>(pf32, wtl, wts, wtm,
        ew, flags, deg);

    conv_lin_kernel<<<N_NODES / 16, 320, 0, stream>>>(x, pf32, wtl, flags, xnb, bufS);

    scanA<<<SCAN_BLOCKS, 1024, 0, stream>>>(deg, rowptr, cntf, bsum);
    scanB<<<1, 1, 0, stream>>>(bsum, boff, SCAN_BLOCKS, rowptr + N_NODES);
    scanC<<<SCAN_BLOCKS, 1024, 0, stream>>>(rowptr, boff, cursor);
    fill_kernel<<<(N_EDGES + 255) / 256, 256, 0, stream>>>(ew, flags, cursor, csr);

    agg0ln_kernel<<<N_NODES / 4, 256, 0, stream>>>(xnb, bufS, rowptr, csr,
        pf32 + OFF_LN_G, pf32 + OFF_LN_B, zb);

    // layer 0: zb -> aggb ; layer 1: aggb -> zb ; layer 2 (fused mlp): zb -> out
    sagefused_kernel<<<N_NODES / 16, 256, 0, stream>>>(zb, rowptr, csr, cntf,
        wts, pf32 + OFF_SAGE_LB,
        pf32 + OFF_LN_G + 128, pf32 + OFF_LN_B + 128, aggb);
    sagefused_kernel<<<N_NODES / 16, 256, 0, stream>>>(aggb, rowptr, csr, cntf,
        wts + 32768, pf32 + OFF_SAGE_LB + 128,
        pf32 + OFF_LN_G + 256, pf32 + OFF_LN_B + 256, zb);
    sagemlp_kernel<<<N_NODES / 16, 256, 0, stream>>>(zb, rowptr, csr, cntf,
        wts + 65536, pf32 + OFF_SAGE_LB + 256, wtm, pf32, flags, d_out);
}

// Round 10
// 1041.807 us; speedup vs baseline: 1.0313x; 1.0313x over previous
//
#include <hip/hip_runtime.h>
#include <hip/hip_bf16.h>

typedef __hip_bfloat16 bf16;
typedef __attribute__((ext_vector_type(8))) short v8s;
typedef __attribute__((ext_vector_type(4))) float v4f;

#define N_NODES 100000
#define N_EDGES 1600000
#define LN_EPS 1e-5f

// f32 param arena offsets (elements)
#define OFF_CONV_W      0
#define OFF_CONV_B      81
#define OFF_CONV_SW     84
#define OFF_CONV_SB     165
#define OFF_LIN_W       168
#define OFF_LIN_B       31272
#define OFF_LIN_SW      31400
#define OFF_LIN_SB      62504
#define OFF_SAGE_LW     62632
#define OFF_SAGE_LB     111784
#define OFF_SAGE_RW     112168
#define OFF_LN_G        161320
#define OFF_LN_B        161704
#define OFF_MLP_W1      162088
#define OFF_MLP_B1      178472
#define OFF_MLP_W2      178600
#define OFF_MLP_B2      179240
#define PARAM_TOTAL     179245

#define WTL_N 65536     // [256 f][256 k]  conv-linear (f<128: lin_w, f>=128: lin_self_w)
#define WTS_N 98304     // 3 x [128 f][256 k]  sage (k<128: lw, k>=128: rw)
#define WTM_N 16384     // [128 f][128 k]  mlp_w1

#define CONV_BLOCKS 6250   // 100000/16
#define DEG_BLOCKS  6250   // 1600000/256
#define SCAN_BLOCKS 98     // ceil(100000/1024)

__device__ __forceinline__ unsigned short f2b(float f) {
    bf16 h = __float2bfloat16(f);
    return __builtin_bit_cast(unsigned short, h);
}
__device__ __forceinline__ float blo(unsigned u) { return __uint_as_float(u << 16); }
__device__ __forceinline__ float bhi(unsigned u) { return __uint_as_float(u & 0xffff0000u); }
__device__ __forceinline__ unsigned pack2(float lo, float hi) {
    return (unsigned)f2b(lo) | ((unsigned)f2b(hi) << 16);
}

struct Ptr17 { const void* p[17]; };

// ---------------- dtype detection ----------------
__global__ void detect_kernel(const unsigned short* __restrict__ xw,
                              const unsigned int* __restrict__ ew,
                              int* __restrict__ flags) {
    __shared__ int sawBigExp, sawHigh;
    if (threadIdx.x == 0) { sawBigExp = 0; sawHigh = 0; }
    __syncthreads();
    int localBig = 0, localHigh = 0;
    for (int i = threadIdx.x; i < 65536; i += 256) {
        unsigned e = (xw[i] >> 7) & 0xFF;
        if (e >= 0xF0) localBig = 1;
    }
    for (int i = threadIdx.x; i < 8192; i += 256) {
        if (ew[2 * i + 1] != 0) localHigh = 1;
    }
    if (localBig) atomicOr(&sawBigExp, 1);
    if (localHigh) atomicOr(&sawHigh, 1);
    __syncthreads();
    if (threadIdx.x == 0) { flags[0] = sawBigExp; flags[1] = sawHigh ? 0 : 1; }
}

// ---------------- convert all float params to f32 arena ----------------
__global__ void cvt_params_kernel(Ptr17 ptrs, const int* __restrict__ flags,
                                  float* __restrict__ dst) {
    int i = blockIdx.x * 256 + threadIdx.x;
    if (i >= PARAM_TOTAL) return;
    const int ksz[17] = {81,3,81,3,31104,128,31104,128,49152,384,49152,384,384,16384,128,640,5};
    int seg = 0, off = i;
    while (off >= ksz[seg]) { off -= ksz[seg]; ++seg; }
    float v;
    if (flags[0]) v = ((const float*)ptrs.p[seg])[off];
    else          v = __bfloat162float(((const bf16*)ptrs.p[seg])[off]);
    dst[i] = v;
}

// ---------------- build bf16 transposed weight arenas ----------------
__global__ void cvt2_kernel(const float* __restrict__ P,
                            unsigned short* __restrict__ wtl,
                            unsigned short* __restrict__ wts,
                            unsigned short* __restrict__ wtm) {
    int i = blockIdx.x * 256 + threadIdx.x;
    if (i < WTL_N) {
        int f = i >> 8, k = i & 255;
        float v = 0.f;
        if (k < 243) v = (f < 128) ? P[OFF_LIN_W + k * 128 + f]
                                   : P[OFF_LIN_SW + k * 128 + (f - 128)];
        wtl[i] = f2b(v);
    } else if (i < WTL_N + WTS_N) {
        int j = i - WTL_N; int l = j >> 15; int r = j & 32767; int f = r >> 8; int k = r & 255;
        float v = (k < 128) ? P[OFF_SAGE_LW + l * 16384 + k * 128 + f]
                            : P[OFF_SAGE_RW + l * 16384 + (k - 128) * 128 + f];
        wts[j] = f2b(v);
    } else if (i < WTL_N + WTS_N + WTM_N) {
        int j = i - WTL_N - WTS_N; int f = j >> 7, k = j & 127;
        wtm[j] = f2b(P[OFF_MLP_W1 + k * 128 + f]);
    }
}

// ---------------- edge loads ----------------
__device__ __forceinline__ int ld_edge(const int* __restrict__ ew, size_t elem, int isi64) {
    size_t idx = isi64 ? (elem * 2) : elem;
    return ew[idx];
}

// ---------------- Stage 1: conv+relu -> linear (MFMA), FUSED with degree count ----------
// R8-verified best home for degree: standalone degree costs ~70us serial (R9 measured);
// fused into conv's grid the marginal cost is only +44us (conv's idle memory pipes
// absorb atomic latency). Blocks >= CONV_BLOCKS do a 256-edge degree slice.
__global__ __launch_bounds__(320) void conv_deg_kernel(
    const void* __restrict__ x, const float* __restrict__ P,
    const unsigned short* __restrict__ wtl, const int* __restrict__ flags,
    const int* __restrict__ ew, int* __restrict__ deg,
    unsigned short* __restrict__ xnb, float* __restrict__ selfh)
{
    if (blockIdx.x >= CONV_BLOCKS) {
        int tid = threadIdx.x;
        if (tid < 256) {
            int e = (blockIdx.x - CONV_BLOCKS) * 256 + tid;
            if (e < N_EDGES) {
                int d = ld_edge(ew, (size_t)N_EDGES + e, flags[1]);
                if ((unsigned)d < N_NODES) atomicAdd(&deg[d], 1);
            }
        }
        return;
    }

    __shared__ unsigned short xs[5808];           // 16 nodes x 363 bf16, flat
    __shared__ unsigned short ysb[16][2][256];    // relu(conv) bf16, K padded to 256
    __shared__ float wc[2][81];
    __shared__ float bc[2][3];
    int tid = threadIdx.x;
    int n0 = blockIdx.x * 16;

    if (tid < 81) { wc[0][tid] = P[OFF_CONV_W + tid]; wc[1][tid] = P[OFF_CONV_SW + tid]; }
    else if (tid < 84) { int o = tid - 81; bc[0][o] = P[OFF_CONV_B + o]; bc[1][o] = P[OFF_CONV_SB + o]; }

    // zero ysb K padding 243..255 (16 j x 2 p x 13 k)
    for (int i = tid; i < 416; i += 320) {
        int j = i / 26, r2 = i % 26, p = r2 / 13, k = 243 + (r2 % 13);
        ysb[j][p][k] = 0;
    }

    if (flags[0]) {
        const float* xf = (const float*)x + (size_t)n0 * 363;
        for (int i = tid; i < 5808; i += 320) xs[i] = f2b(xf[i]);
    } else {
        const uint4* xsrc = (const uint4*)((const unsigned short*)x + (size_t)n0 * 363);
        uint4* xd = (uint4*)xs;
        for (int i = tid; i < 726; i += 320) xd[i] = xsrc[i];
    }
    __syncthreads();

    // conv: one unit per thread: (node j, path p, output row oi) -> 27 outputs
    if (tid < 288) {
        int j = tid / 18, rem = tid % 18;
        int p = rem / 9, oi = rem % 9;
        float acc[27];
        #pragma unroll
        for (int o = 0; o < 3; o++) {
            float b = bc[p][o];
            #pragma unroll
            for (int oj = 0; oj < 9; oj++) acc[o * 9 + oj] = b;
        }
        #pragma unroll
        for (int c = 0; c < 3; c++) {
            #pragma unroll
            for (int ki = 0; ki < 3; ki++) {
                float xr[11];
                const unsigned short* row = &xs[j * 363 + c * 121 + (oi + ki) * 11];
                #pragma unroll
                for (int t = 0; t < 11; t++) xr[t] = blo(row[t]);
                #pragma unroll
                for (int o = 0; o < 3; o++) {
                    int wb = o * 27 + c * 9 + ki * 3;
                    float w0 = wc[p][wb], w1 = wc[p][wb + 1], w2 = wc[p][wb + 2];
                    #pragma unroll
                    for (int oj = 0; oj < 9; oj++)
                        acc[o * 9 + oj] += xr[oj] * w0 + xr[oj + 1] * w1 + xr[oj + 2] * w2;
                }
            }
        }
        #pragma unroll
        for (int o = 0; o < 3; o++)
            #pragma unroll
            for (int oj = 0; oj < 9; oj++)
                ysb[j][p][o * 81 + oi * 9 + oj] = f2b(fmaxf(acc[o * 9 + oj], 0.f));
    }
    __syncthreads();

    // MFMA: [16 nodes][256 k] x [256 k][256 f]; waves 0-1 -> path0 (f 0..127), 2-3 -> path1
    int wave = tid >> 6, lane = tid & 63, quad = lane >> 4, col = lane & 15;
    if (wave < 4) {
        int p = wave >> 1;
        v4f acc[4];
        #pragma unroll
        for (int t = 0; t < 4; t++) { acc[t][0] = 0.f; acc[t][1] = 0.f; acc[t][2] = 0.f; acc[t][3] = 0.f; }
        for (int s = 0; s < 8; s++) {
            int kq = s * 32 + quad * 8;
            v8s a = *(const v8s*)&ysb[col][p][kq];
            #pragma unroll
            for (int t = 0; t < 4; t++) {
                int f = (wave * 4 + t) * 16 + col;
                v8s b = *(const v8s*)&wtl[(size_t)f * 256 + kq];
                acc[t] = __builtin_amdgcn_mfma_f32_16x16x32_bf16(a, b, acc[t], 0, 0, 0);
            }
        }
        #pragma unroll
        for (int t = 0; t < 4; t++) {
            int f = (wave * 4 + t) * 16 + col;
            #pragma unroll
            for (int r = 0; r < 4; r++) {
                int node = n0 + quad * 4 + r;
                float v = acc[t][r];
                if (p == 0) xnb[(size_t)node * 128 + f] = f2b(v + P[OFF_LIN_B + f]);
                else        selfh[(size_t)node * 128 + (f - 128)] = v + P[OFF_LIN_SB + (f - 128)];
            }
        }
    }
}

// ---------------- CSR build ----------------
__global__ __launch_bounds__(1024) void scanA(const int* __restrict__ deg, int* __restrict__ rowptr,
                                              float* __restrict__ cntf, int* __restrict__ bsum) {
    __shared__ int s[1024];
    int tid = threadIdx.x;
    int i = blockIdx.x * 1024 + tid;
    int v = (i < N_NODES) ? deg[i] : 0;
    s[tid] = v;
    __syncthreads();
    for (int off = 1; off < 1024; off <<= 1) {
        int t = (tid >= off) ? s[tid - off] : 0;
        __syncthreads();
        s[tid] += t;
        __syncthreads();
    }
    if (i < N_NODES) {
        rowptr[i] = s[tid] - v;
        cntf[i] = (float)(v < 1 ? 1 : v);
    }
    if (tid == 1023) bsum[blockIdx.x] = s[1023];
}

// scanC with scanB merged: each block computes its own boff from bsum (98 entries,
// LDS broadcast loop ~100cyc); last block also writes rowptr[N_NODES] = total.
__global__ __launch_bounds__(1024) void scanC(int* __restrict__ rowptr, const int* __restrict__ bsum,
                                              int* __restrict__ cursor) {
    __shared__ int sb[128];
    int tid = threadIdx.x;
    if (tid < SCAN_BLOCKS) sb[tid] = bsum[tid];
    __syncthreads();
    int boff = 0;
    for (int k = 0; k < blockIdx.x; k++) boff += sb[k];   // uniform, LDS broadcast
    int i = blockIdx.x * 1024 + tid;
    if (i < N_NODES) {
        int v = rowptr[i] + boff;
        rowptr[i] = v;
        cursor[i] = v;
    }
    if (blockIdx.x == SCAN_BLOCKS - 1 && tid == 0) {
        int tot = 0;
        for (int k = 0; k < SCAN_BLOCKS; k++) tot += sb[k];
        rowptr[N_NODES] = tot;
    }
}

__global__ void fill_kernel(const int* __restrict__ ew, const int* __restrict__ flags,
                            int* __restrict__ cursor, int* __restrict__ csr) {
    int e = blockIdx.x * blockDim.x + threadIdx.x;
    if (e < N_EDGES) {
        int isi64 = flags[1];
        int s = ld_edge(ew, (size_t)e, isi64);
        int d = ld_edge(ew, (size_t)N_EDGES + e, isi64);
        if ((unsigned)d < N_NODES) {
            int p = atomicAdd(&cursor[d], 1);
            if ((unsigned)p < N_EDGES)
                csr[p] = ((unsigned)s < N_NODES) ? (s | ((s == d) ? (int)0x80000000 : 0)) : -1;
        }
    }
}

// ---------------- agg0 + relu + LN0 ----------------
__global__ __launch_bounds__(256) void agg0ln_kernel(const unsigned short* __restrict__ xnb,
        const float* __restrict__ selfh, const int* __restrict__ rowptr, const int* __restrict__ csr,
        const float* __restrict__ lng, const float* __restrict__ lnb,
        unsigned short* __restrict__ zb) {
    int wave = threadIdx.x >> 6, lane = threadIdx.x & 63;
    int g = lane >> 4, c = lane & 15;
    int n = blockIdx.x * 4 + wave;
    int beg = rowptr[n], end = rowptr[n + 1];
    float a[8];
    #pragma unroll
    for (int i = 0; i < 8; i++) a[i] = 0.f;
    const uint4* x4 = (const uint4*)xnb;
    for (int b = beg; b < end; b += 64) {
        int bl = b + lane;
        int my = (bl < end) ? csr[bl] : -1;
        int nb = end - b; if (nb > 64) nb = 64;
        for (int i = 0; i < nb; i += 16) {
            int sv0 = __shfl(my, i + g, 64);
            int sv1 = __shfl(my, i + 4 + g, 64);
            int sv2 = __shfl(my, i + 8 + g, 64);
            int sv3 = __shfl(my, i + 12 + g, 64);
            bool va0 = ((unsigned)sv0 < N_NODES);
            bool va1 = ((unsigned)sv1 < N_NODES);
            bool va2 = ((unsigned)sv2 < N_NODES);
            bool va3 = ((unsigned)sv3 < N_NODES);
            uint4 v0 = x4[(size_t)(va0 ? sv0 : 0) * 16 + c];
            uint4 v1 = x4[(size_t)(va1 ? sv1 : 0) * 16 + c];
            uint4 v2 = x4[(size_t)(va2 ? sv2 : 0) * 16 + c];
            uint4 v3 = x4[(size_t)(va3 ? sv3 : 0) * 16 + c];
            if (va0) {
                a[0] += blo(v0.x); a[1] += bhi(v0.x);
                a[2] += blo(v0.y); a[3] += bhi(v0.y);
                a[4] += blo(v0.z); a[5] += bhi(v0.z);
                a[6] += blo(v0.w); a[7] += bhi(v0.w);
            }
            if (va1) {
                a[0] += blo(v1.x); a[1] += bhi(v1.x);
                a[2] += blo(v1.y); a[3] += bhi(v1.y);
                a[4] += blo(v1.z); a[5] += bhi(v1.z);
                a[6] += blo(v1.w); a[7] += bhi(v1.w);
            }
            if (va2) {
                a[0] += blo(v2.x); a[1] += bhi(v2.x);
                a[2] += blo(v2.y); a[3] += bhi(v2.y);
                a[4] += blo(v2.z); a[5] += bhi(v2.z);
                a[6] += blo(v2.w); a[7] += bhi(v2.w);
            }
            if (va3) {
                a[0] += blo(v3.x); a[1] += bhi(v3.x);
                a[2] += blo(v3.y); a[3] += bhi(v3.y);
                a[4] += blo(v3.z); a[5] += bhi(v3.z);
                a[6] += blo(v3.w); a[7] += bhi(v3.w);
            }
        }
    }
    #pragma unroll
    for (int i = 0; i < 8; i++) {
        a[i] += __shfl_xor(a[i], 16, 64);
        a[i] += __shfl_xor(a[i], 32, 64);
    }
    if (g == 0) {
        const float4* s4 = (const float4*)(selfh + (size_t)n * 128 + c * 8);
        float4 s0 = s4[0], s1 = s4[1];
        float v[8];
        v[0] = s0.x + a[0]; v[1] = s0.y + a[1]; v[2] = s0.z + a[2]; v[3] = s0.w + a[3];
        v[4] = s1.x + a[4]; v[5] = s1.y + a[5]; v[6] = s1.z + a[6]; v[7] = s1.w + a[7];
        float s = 0.f, sq = 0.f;
        #pragma unroll
        for (int i = 0; i < 8; i++) {
            v[i] = fmaxf(v[i], 0.f);
            s += v[i]; sq += v[i] * v[i];
        }
        #pragma unroll
        for (int m = 8; m >= 1; m >>= 1) {
            s  += __shfl_xor(s, m, 64);
            sq += __shfl_xor(sq, m, 64);
        }
        float mu = s * (1.f / 128.f);
        float var = sq * (1.f / 128.f) - mu * mu;
        float is = rsqrtf(var + LN_EPS);
        const float4* g4 = (const float4*)(lng + c * 8);
        const float4* b4 = (const float4*)(lnb + c * 8);
        float4 g0 = g4[0], g1 = g4[1], b0 = b4[0], b1 = b4[1];
        float z[8];
        z[0] = (v[0] - mu) * is * g0.x + b0.x; z[1] = (v[1] - mu) * is * g0.y + b0.y;
        z[2] = (v[2] - mu) * is * g0.z + b0.z; z[3] = (v[3] - mu) * is * g0.w + b0.w;
        z[4] = (v[4] - mu) * is * g1.x + b1.x; z[5] = (v[5] - mu) * is * g1.y + b1.y;
        z[6] = (v[6] - mu) * is * g1.z + b1.z; z[7] = (v[7] - mu) * is * g1.w + b1.w;
        uint4 o;
        o.x = pack2(z[0], z[1]); o.y = pack2(z[2], z[3]);
        o.z = pack2(z[4], z[5]); o.w = pack2(z[6], z[7]);
        ((uint4*)zb)[(size_t)n * 16 + c] = o;
    }
}

// ---------------- gather helper: mean-aggregate 4 nodes per wave into LDS ----------------
__device__ __forceinline__ void sage_gather(const unsigned short* __restrict__ cur,
        const int* __restrict__ rowptr, const int* __restrict__ csr,
        const float* __restrict__ cntf, int n0, int wave, int lane, int g, int c,
        unsigned short al[16][128]) {
    const uint4* z4 = (const uint4*)cur;
    for (int q = 0; q < 4; q++) {
        int jj = wave * 4 + q;
        int n = n0 + jj;
        int beg = rowptr[n], end = rowptr[n + 1];
        float a[8];
        #pragma unroll
        for (int i = 0; i < 8; i++) a[i] = 0.f;
        for (int b = beg; b < end; b += 64) {
            int bl = b + lane;
            int my = (bl < end) ? csr[bl] : -1;
            int nb = end - b; if (nb > 64) nb = 64;
            for (int i = 0; i < nb; i += 16) {
                int sv0 = __shfl(my, i + g, 64) & 0x7fffffff;      // SAGE keeps self loops
                int sv1 = __shfl(my, i + 4 + g, 64) & 0x7fffffff;
                int sv2 = __shfl(my, i + 8 + g, 64) & 0x7fffffff;
                int sv3 = __shfl(my, i + 12 + g, 64) & 0x7fffffff;
                bool va0 = (sv0 < N_NODES);
                bool va1 = (sv1 < N_NODES);
                bool va2 = (sv2 < N_NODES);
                bool va3 = (sv3 < N_NODES);
                uint4 v0 = z4[(size_t)(va0 ? sv0 : 0) * 16 + c];
                uint4 v1 = z4[(size_t)(va1 ? sv1 : 0) * 16 + c];
                uint4 v2 = z4[(size_t)(va2 ? sv2 : 0) * 16 + c];
                uint4 v3 = z4[(size_t)(va3 ? sv3 : 0) * 16 + c];
                if (va0) {
                    a[0] += blo(v0.x); a[1] += bhi(v0.x);
                    a[2] += blo(v0.y); a[3] += bhi(v0.y);
                    a[4] += blo(v0.z); a[5] += bhi(v0.z);
                    a[6] += blo(v0.w); a[7] += bhi(v0.w);
                }
                if (va1) {
                    a[0] += blo(v1.x); a[1] += bhi(v1.x);
                    a[2] += blo(v1.y); a[3] += bhi(v1.y);
                    a[4] += blo(v1.z); a[5] += bhi(v1.z);
                    a[6] += blo(v1.w); a[7] += bhi(v1.w);
                }
                if (va2) {
                    a[0] += blo(v2.x); a[1] += bhi(v2.x);
                    a[2] += blo(v2.y); a[3] += bhi(v2.y);
                    a[4] += blo(v2.z); a[5] += bhi(v2.z);
                    a[6] += blo(v2.w); a[7] += bhi(v2.w);
                }
                if (va3) {
                    a[0] += blo(v3.x); a[1] += bhi(v3.x);
                    a[2] += blo(v3.y); a[3] += bhi(v3.y);
                    a[4] += blo(v3.z); a[5] += bhi(v3.z);
                    a[6] += blo(v3.w); a[7] += bhi(v3.w);
                }
            }
        }
        #pragma unroll
        for (int i = 0; i < 8; i++) {
            a[i] += __shfl_xor(a[i], 16, 64);
            a[i] += __shfl_xor(a[i], 32, 64);
        }
        if (g == 0) {
            float inv = 1.f / cntf[n];
            uint4 o;
            o.x = pack2(a[0] * inv, a[1] * inv); o.y = pack2(a[2] * inv, a[3] * inv);
            o.z = pack2(a[4] * inv, a[5] * inv); o.w = pack2(a[6] * inv, a[7] * inv);
            ((uint4*)&al[jj][0])[c] = o;
        }
    }
}

// ---------------- FUSED SAGE layer 0/1: gather + MFMA + relu+LN ----------------
__global__ __launch_bounds__(256) void sagefused_kernel(
        const unsigned short* __restrict__ cur,
        const int* __restrict__ rowptr, const int* __restrict__ csr,
        const float* __restrict__ cntf, const unsigned short* __restrict__ wts,
        const float* __restrict__ lb, const float* __restrict__ lng, const float* __restrict__ lnb,
        unsigned short* __restrict__ nxt) {
    __shared__ unsigned short al[16][128];   // bf16 mean-aggregated features
    __shared__ float hb[16][128];
    int tid = threadIdx.x;
    int n0 = blockIdx.x * 16;
    int wave = tid >> 6, lane = tid & 63;
    int g = lane >> 4, c = lane & 15;

    sage_gather(cur, rowptr, csr, cntf, n0, wave, lane, g, c, al);
    __syncthreads();

    // MFMA (concat-K: agg from LDS, root from cur)
    int quad = g, col = c;
    int nodeA = n0 + col;
    v4f acc[2];
    #pragma unroll
    for (int t = 0; t < 2; t++) { acc[t][0] = 0.f; acc[t][1] = 0.f; acc[t][2] = 0.f; acc[t][3] = 0.f; }
    #pragma unroll
    for (int s = 0; s < 8; s++) {
        int kq = s * 32 + quad * 8;
        const unsigned short* abase = (s < 4) ? &al[col][kq]
                                              : (cur + (size_t)nodeA * 128 + (kq - 128));
        v8s a = *(const v8s*)abase;
        #pragma unroll
        for (int t = 0; t < 2; t++) {
            int f = (wave * 2 + t) * 16 + col;
            v8s b = *(const v8s*)&wts[(size_t)f * 256 + kq];
            acc[t] = __builtin_amdgcn_mfma_f32_16x16x32_bf16(a, b, acc[t], 0, 0, 0);
        }
    }
    #pragma unroll
    for (int t = 0; t < 2; t++) {
        int f = (wave * 2 + t) * 16 + col;
        float bias = lb[f];
        #pragma unroll
        for (int r = 0; r < 4; r++)
            hb[quad * 4 + r][f] = acc[t][r] + bias;
    }
    __syncthreads();

    // relu + LN
    #pragma unroll
    for (int jj = 0; jj < 4; jj++) {
        int j = wave * 4 + jj;
        int node = n0 + j;
        float v0 = hb[j][2 * lane], v1 = hb[j][2 * lane + 1];
        float r0 = fmaxf(v0, 0.f), r1 = fmaxf(v1, 0.f);
        float s = r0 + r1, sq = r0 * r0 + r1 * r1;
        #pragma unroll
        for (int m = 32; m >= 1; m >>= 1) {
            s  += __shfl_xor(s, m, 64);
            sq += __shfl_xor(sq, m, 64);
        }
        float mu = s * (1.f / 128.f);
        float var = sq * (1.f / 128.f) - mu * mu;
        float inv = rsqrtf(var + LN_EPS);
        float z0 = (r0 - mu) * inv * lng[2 * lane]     + lnb[2 * lane];
        float z1 = (r1 - mu) * inv * lng[2 * lane + 1] + lnb[2 * lane + 1];
        ((unsigned int*)nxt)[(size_t)node * 64 + lane] = pack2(z0, z1);
    }
}

// ---------------- FUSED last SAGE layer + MLP head + log_softmax + emb out ----------------
__global__ __launch_bounds__(256) void sagemlp_kernel(
        const unsigned short* __restrict__ cur,
        const int* __restrict__ rowptr, const int* __restrict__ csr,
        const float* __restrict__ cntf, const unsigned short* __restrict__ wts,
        const float* __restrict__ lb, const unsigned short* __restrict__ wtm,
        const float* __restrict__ P, const int* __restrict__ flags,
        void* __restrict__ out) {
    __shared__ unsigned short al[16][128];
    __shared__ float hb[16][128];
    __shared__ unsigned short rb[16][128];
    __shared__ float mb[16][128];
    __shared__ float lg[16][5];
    int tid = threadIdx.x;
    int n0 = blockIdx.x * 16;
    int wave = tid >> 6, lane = tid & 63;
    int g = lane >> 4, c = lane & 15;
    int isf = flags[0];

    sage_gather(cur, rowptr, csr, cntf, n0, wave, lane, g, c, al);
    __syncthreads();

    // SAGE MFMA -> hb (final h, f32)
    int quad = g, col = c;
    int nodeA = n0 + col;
    v4f acc[2];
    #pragma unroll
    for (int t = 0; t < 2; t++) { acc[t][0] = 0.f; acc[t][1] = 0.f; acc[t][2] = 0.f; acc[t][3] = 0.f; }
    #pragma unroll
    for (int s = 0; s < 8; s++) {
        int kq = s * 32 + quad * 8;
        const unsigned short* abase = (s < 4) ? &al[col][kq]
                                              : (cur + (size_t)nodeA * 128 + (kq - 128));
        v8s a = *(const v8s*)abase;
        #pragma unroll
        for (int t = 0; t < 2; t++) {
            int f = (wave * 2 + t) * 16 + col;
            v8s b = *(const v8s*)&wts[(size_t)f * 256 + kq];
            acc[t] = __builtin_amdgcn_mfma_f32_16x16x32_bf16(a, b, acc[t], 0, 0, 0);
        }
    }
    #pragma unroll
    for (int t = 0; t < 2; t++) {
        int f = (wave * 2 + t) * 16 + col;
        float bias = lb[f];
        #pragma unroll
        for (int r = 0; r < 4; r++)
            hb[quad * 4 + r][f] = acc[t][r] + bias;
    }
    __syncthreads();

    // mlp front: emb output write + relu -> rb (bf16)
    for (int i = tid; i < 16 * 64; i += 256) {
        int j = i >> 6, q = i & 63;
        float vx = hb[j][2 * q], vy = hb[j][2 * q + 1];
        size_t oi = (size_t)(n0 + j) * 128 + 2 * q;
        if (isf) { ((float*)out)[oi] = vx; ((float*)out)[oi + 1] = vy; }
        else ((unsigned int*)out)[oi >> 1] = pack2(vx, vy);
        rb[j][2 * q]     = f2b(fmaxf(vx, 0.f));
        rb[j][2 * q + 1] = f2b(fmaxf(vy, 0.f));
    }
    __syncthreads();

    // mlp MFMA (rb x wtm)
    v4f acc2[2];
    #pragma unroll
    for (int t = 0; t < 2; t++) { acc2[t][0] = 0.f; acc2[t][1] = 0.f; acc2[t][2] = 0.f; acc2[t][3] = 0.f; }
    #pragma unroll
    for (int s = 0; s < 4; s++) {
        int kq = s * 32 + quad * 8;
        v8s a = *(const v8s*)&rb[col][kq];
        #pragma unroll
        for (int t = 0; t < 2; t++) {
            int f = (wave * 2 + t) * 16 + col;
            v8s b = *(const v8s*)&wtm[(size_t)f * 128 + kq];
            acc2[t] = __builtin_amdgcn_mfma_f32_16x16x32_bf16(a, b, acc2[t], 0, 0, 0);
        }
    }
    #pragma unroll
    for (int t = 0; t < 2; t++) {
        int f = (wave * 2 + t) * 16 + col;
        float bias = P[OFF_MLP_B1 + f];
        #pragma unroll
        for (int r = 0; r < 4; r++)
            mb[quad * 4 + r][f] = acc2[t][r] + bias;
    }
    __syncthreads();

    if (tid < 80) {
        int j = tid / 5, o = tid - (tid / 5) * 5;
        float a = P[OFF_MLP_B2 + o];
        for (int k = 0; k < 128; k++) a += mb[j][k] * P[OFF_MLP_W2 + k * 5 + o];
        lg[j][o] = a;
    }
    __syncthreads();
    if (tid < 16) {
        int j = tid;
        float mx = lg[j][0];
        #pragma unroll
        for (int o = 1; o < 5; o++) mx = fmaxf(mx, lg[j][o]);
        float se = 0.f;
        #pragma unroll
        for (int o = 0; o < 5; o++) se += expf(lg[j][o] - mx);
        float lse = mx + logf(se);
        size_t base = (size_t)N_NODES * 128 + (size_t)(n0 + j) * 5;
        #pragma unroll
        for (int o = 0; o < 5; o++) {
            float v = lg[j][o] - lse;
            if (isf) ((float*)out)[base + o] = v;
            else     ((bf16*)out)[base + o] = __float2bfloat16(v);
        }
    }
}

extern "C" void kernel_launch(void* const* d_in, const int* in_sizes, int n_in,
                              void* d_out, int out_size, void* d_ws, size_t ws_size,
                              hipStream_t stream) {
    const void* x  = d_in[0];
    const int*  ew = (const int*)d_in[1];

    Ptr17 ptrs;
    for (int i = 0; i < 17; i++) ptrs.p[i] = d_in[2 + i];

    char* w = (char*)d_ws;
    auto carve = [&](size_t bytes) { char* r = w; w += (bytes + 255) & ~(size_t)255; return r; };
    float*          bufS  = (float*)carve((size_t)N_NODES * 128 * 4);   // selfh
    unsigned short* xnb   = (unsigned short*)carve((size_t)N_NODES * 128 * 2);
    unsigned short* zb    = (unsigned short*)carve((size_t)N_NODES * 128 * 2);
    unsigned short* aggb  = (unsigned short*)carve((size_t)N_NODES * 128 * 2);
    float*          pf32  = (float*)carve((size_t)PARAM_TOTAL * 4);
    unsigned short* wtl   = (unsigned short*)carve((size_t)WTL_N * 2);
    unsigned short* wts   = (unsigned short*)carve((size_t)WTS_N * 2);
    unsigned short* wtm   = (unsigned short*)carve((size_t)WTM_N * 2);
    int*   deg    = (int*)carve((size_t)N_NODES * 4);
    int*   rowptr = (int*)carve((size_t)(N_NODES + 64) * 4);
    int*   cursor = (int*)carve((size_t)N_NODES * 4);
    float* cntf   = (float*)carve((size_t)N_NODES * 4);
    int*   bsum   = (int*)carve(512);
    int*   boff   = (int*)carve(512);
    int*   flags  = (int*)carve(256);
    int*   csr    = (int*)carve((size_t)N_EDGES * 4);

    detect_kernel<<<1, 256, 0, stream>>>((const unsigned short*)x, (const unsigned int*)ew, flags);
    cvt_params_kernel<<<(PARAM_TOTAL + 255) / 256, 256, 0, stream>>>(ptrs, flags, pf32);
    cvt2_kernel<<<(WTL_N + WTS_N + WTM_N + 255) / 256, 256, 0, stream>>>(pf32, wtl, wts, wtm);

    hipMemsetAsync(deg, 0, (size_t)N_NODES * 4, stream);

    conv_deg_kernel<<<CONV_BLOCKS + DEG_BLOCKS, 320, 0, stream>>>(x, pf32, wtl, flags,
        ew, deg, xnb, bufS);

    scanA<<<SCAN_BLOCKS, 1024, 0, stream>>>(deg, rowptr, cntf, bsum);
    scanC<<<SCAN_BLOCKS, 1024, 0, stream>>>(rowptr, bsum, cursor);
    fill_kernel<<<(N_EDGES + 255) / 256, 256, 0, stream>>>(ew, flags, cursor, csr);

    agg0ln_kernel<<<N_NODES / 4, 256, 0, stream>>>(xnb, bufS, rowptr, csr,
        pf32 + OFF_LN_G, pf32 + OFF_LN_B, zb);

    // layer 0: zb -> aggb ; layer 1: aggb -> zb ; layer 2 (fused mlp): zb -> out
    sagefused_kernel<<<N_NODES / 16, 256, 0, stream>>>(zb, rowptr, csr, cntf,
        wts, pf32 + OFF_SAGE_LB,
        pf32 + OFF_LN_G + 128, pf32 + OFF_LN_B + 128, aggb);
    sagefused_kernel<<<N_NODES / 16, 256, 0, stream>>>(aggb, rowptr, csr, cntf,
        wts + 32768, pf32 + OFF_SAGE_LB + 128,
        pf32 + OFF_LN_G + 256, pf32 + OFF_LN_B + 256, zb);
    sagemlp_kernel<<<N_NODES / 16, 256, 0, stream>>>(zb, rowptr, csr, cntf,
        wts + 65536, pf32 + OFF_SAGE_LB + 256, wtm, pf32, flags, d_out);
}